// Round 8
// baseline (450.361 us; speedup 1.0000x reference)
//
#include <hip/hip_runtime.h>
#include <cstdint>
#include <cstddef>

typedef __bf16 bf16x8 __attribute__((ext_vector_type(8)));
typedef float f32x4 __attribute__((ext_vector_type(4)));
typedef float f32x16 __attribute__((ext_vector_type(16)));
typedef unsigned short u16;
typedef unsigned uint2v __attribute__((ext_vector_type(2)));

namespace {
constexpr int Bb = 4, Tt = 2048, Cc = 1024, Hh = 16, Dd = 64;
constexpr int ROWS = Bb * Tt;   // 8192
constexpr int C3 = 3 * Cc;      // 3072
constexpr float LNEPS = 1e-5f;
constexpr float SCL2 = 0.18033688011112042f; // 0.125 * log2(e)
}

__device__ __forceinline__ u16 f2bf(float f) {
  union { float f; unsigned u; } v; v.f = f;
  return (u16)((v.u + 0x7fffu + ((v.u >> 16) & 1u)) >> 16);
}
__device__ __forceinline__ u16 bfn(float f) {
  union { __bf16 b; u16 u; } t; t.b = (__bf16)f; return t.u;
}
__device__ __forceinline__ unsigned pk2(float lo, float hi) {
  union { __bf16 b[2]; unsigned u; } t;
  t.b[0] = (__bf16)lo; t.b[1] = (__bf16)hi;
  return t.u;
}
__device__ __forceinline__ float exp2_hw(float x) {
  float r;
  asm("v_exp_f32 %0, %1" : "=v"(r) : "v"(x));
  return r;
}
__device__ __forceinline__ uint2v plswap(unsigned a, unsigned b) {
  return __builtin_amdgcn_permlane32_swap(a, b, false, false);
}
__device__ __forceinline__ float xhalf_max(float x) {
  union { float f; unsigned u; } c; c.f = x;
  uint2v r = plswap(c.u, c.u);
  union { unsigned u; float f; } a, b; a.u = r[0]; b.u = r[1];
  return fmaxf(a.f, b.f);
}
__device__ __forceinline__ float xhalf_sum(float x) {
  union { float f; unsigned u; } c; c.f = x;
  uint2v r = plswap(c.u, c.u);
  union { unsigned u; float f; } a, b; a.u = r[0]; b.u = r[1];
  return a.f + b.f;
}

typedef __attribute__((address_space(3))) unsigned lds_u32;
typedef __attribute__((address_space(1))) const unsigned glb_u32;
__device__ __forceinline__ void gload_lds16(const u16* g, u16* l) {
  __builtin_amdgcn_global_load_lds((glb_u32*)g, (lds_u32*)l, 16, 0, 0);
}

// ---------------- LayerNorm (fp32 in -> bf16 out) ----------------
__global__ __launch_bounds__(256) void ln_kernel(
    const float* __restrict__ x, const float* __restrict__ g,
    const float* __restrict__ b, u16* __restrict__ out)
{
  const int row = blockIdx.x;
  const int tid = threadIdx.x;
  const float4 v = reinterpret_cast<const float4*>(x + (size_t)row * Cc)[tid];
  float s  = v.x + v.y + v.z + v.w;
  float ss = v.x * v.x + v.y * v.y + v.z * v.z + v.w * v.w;
#pragma unroll
  for (int off = 32; off; off >>= 1) {
    s  += __shfl_xor(s, off);
    ss += __shfl_xor(ss, off);
  }
  __shared__ float sa[4], sb[4];
  const int w = tid >> 6;
  if ((tid & 63) == 0) { sa[w] = s; sb[w] = ss; }
  __syncthreads();
  s  = sa[0] + sa[1] + sa[2] + sa[3];
  ss = sb[0] + sb[1] + sb[2] + sb[3];
  const float mu   = s * (1.0f / Cc);
  const float var  = ss * (1.0f / Cc) - mu * mu;
  const float rstd = rsqrtf(var + LNEPS);
  const float4 gv = reinterpret_cast<const float4*>(g)[tid];
  const float4 bv = reinterpret_cast<const float4*>(b)[tid];
  ushort4 o;
  o.x = f2bf((v.x - mu) * rstd * gv.x + bv.x);
  o.y = f2bf((v.y - mu) * rstd * gv.y + bv.y);
  o.z = f2bf((v.z - mu) * rstd * gv.z + bv.z);
  o.w = f2bf((v.w - mu) * rstd * gv.w + bv.w);
  reinterpret_cast<ushort4*>(out + (size_t)row * Cc)[tid] = o;
}

// ---------------- weight transpose + cast: w[K][N] f32 -> wt[N][K] bf16 ----------------
__global__ __launch_bounds__(256) void wcast_t(
    const float* __restrict__ w, u16* __restrict__ wt, int K, int N)
{
  __shared__ float tile[32][33];
  const int n0 = blockIdx.x * 32, k0 = blockIdx.y * 32;
  const int tx = threadIdx.x & 31, ty = threadIdx.x >> 5; // 32x8
#pragma unroll
  for (int i = 0; i < 4; i++)
    tile[ty + i * 8][tx] = w[(size_t)(k0 + ty + i * 8) * N + n0 + tx];
  __syncthreads();
#pragma unroll
  for (int i = 0; i < 4; i++)
    wt[(size_t)(n0 + ty + i * 8) * K + k0 + tx] = f2bf(tile[tx][ty + i * 8]);
}

enum { EPI_BIAS_BF16 = 0, EPI_BIAS_RELU_BF16 = 1, EPI_BIAS_RES_F32 = 2 };

// ---------------- GEMM 256x256, 4-slot ring, counted vmcnt (unchanged R7) ----------------
template <int EPI>
__global__ __launch_bounds__(512, 2) void gemm256(
    const u16* __restrict__ A, const u16* __restrict__ Bt,
    const float* __restrict__ bias, const float* __restrict__ res,
    void* __restrict__ outp, int M, int N, int K)
{
  __shared__ alignas(16) u16 Al[4][256 * 32];
  __shared__ alignas(16) u16 Bl[4][256 * 32];

  const int tid  = threadIdx.x;
  const int lane = tid & 63;
  const int wv   = tid >> 6;            // 8 waves: 2M x 4N
  const int wr   = wv >> 2, wc = wv & 3;
  const int lr   = lane & 15;
  const int lg   = (lane >> 4) & 3;

  const int q8  = (int)gridDim.x >> 3;
  const int lid = ((int)blockIdx.x & 7) * q8 + ((int)blockIdx.x >> 3);
  const int bm = (lid & 31) << 8;       // M/256 == 32 fixed
  const int bn = (lid >> 5) << 8;

  const int srl  = tid >> 2;                       // 0..127
  const int schk = (tid & 3) ^ ((tid >> 3) & 3);
  const u16* gA = A  + (size_t)(bm + srl) * K + schk * 8;
  const u16* gB = Bt + (size_t)(bn + srl) * K + schk * 8;
  const size_t rowK128 = (size_t)128 * K;

  const int fsw  = (lg ^ ((lr >> 1) & 3)) * 8;
  const int arow = wr * 128 + lr;       // + mi*16
  const int brow = wc * 64 + lr;        // + nj*16

  f32x4 acc[8][4];
#pragma unroll
  for (int mi = 0; mi < 8; mi++)
#pragma unroll
    for (int nj = 0; nj < 4; nj++)
      acc[mi][nj] = (f32x4){0.f, 0.f, 0.f, 0.f};

  const int NT = K >> 5;

  auto stageA = [&](int t) {
    u16* d = &Al[t & 3][tid * 8];
    gload_lds16(gA + (size_t)t * 32, d);
    gload_lds16(gA + rowK128 + (size_t)t * 32, d + 4096);
  };
  auto stageB = [&](int t) {
    u16* d = &Bl[t & 3][tid * 8];
    gload_lds16(gB + (size_t)t * 32, d);
    gload_lds16(gB + rowK128 + (size_t)t * 32, d + 4096);
  };

  for (int t = 0; t < 3; ++t) { stageA(t); stageB(t); }
  asm volatile("s_waitcnt vmcnt(8)" ::: "memory");
  asm volatile("s_barrier" ::: "memory");

  for (int kt = 0; kt < NT; ++kt) {
    const u16* Ab = &Al[kt & 3][0];
    const u16* Bb = &Bl[kt & 3][0];
    const bool st = (kt + 3 < NT);

    bf16x8 bf[4];
#pragma unroll
    for (int nj = 0; nj < 4; ++nj)
      bf[nj] = *reinterpret_cast<const bf16x8*>(Bb + (brow + nj * 16) * 32 + fsw);
    bf16x8 af[4];
#pragma unroll
    for (int m = 0; m < 4; ++m)
      af[m] = *reinterpret_cast<const bf16x8*>(Ab + (arow + m * 16) * 32 + fsw);
    if (st) stageA(kt + 3);
    asm volatile("s_barrier" ::: "memory");
    __builtin_amdgcn_s_setprio(1);
#pragma unroll
    for (int m = 0; m < 4; ++m)
#pragma unroll
      for (int nj = 0; nj < 4; ++nj)
        acc[m][nj] = __builtin_amdgcn_mfma_f32_16x16x32_bf16(af[m], bf[nj], acc[m][nj], 0, 0, 0);
    __builtin_amdgcn_s_setprio(0);
    asm volatile("s_barrier" ::: "memory");

#pragma unroll
    for (int m = 0; m < 4; ++m)
      af[m] = *reinterpret_cast<const bf16x8*>(Ab + (arow + (m + 4) * 16) * 32 + fsw);
    if (st) stageB(kt + 3);
    if (kt < NT - 3)       { asm volatile("s_waitcnt vmcnt(8)" ::: "memory"); }
    else if (kt == NT - 3) { asm volatile("s_waitcnt vmcnt(4)" ::: "memory"); }
    else if (kt == NT - 2) { asm volatile("s_waitcnt vmcnt(0)" ::: "memory"); }
    asm volatile("s_barrier" ::: "memory");
    __builtin_amdgcn_s_setprio(1);
#pragma unroll
    for (int m = 0; m < 4; ++m)
#pragma unroll
      for (int nj = 0; nj < 4; ++nj)
        acc[m + 4][nj] = __builtin_amdgcn_mfma_f32_16x16x32_bf16(af[m], bf[nj], acc[m + 4][nj], 0, 0, 0);
    __builtin_amdgcn_s_setprio(0);
    asm volatile("s_barrier" ::: "memory");
  }

#pragma unroll
  for (int mi = 0; mi < 8; ++mi) {
    const int row0 = bm + wr * 128 + mi * 16 + lg * 4;
#pragma unroll
    for (int nj = 0; nj < 4; ++nj) {
      const int col = bn + wc * 64 + nj * 16 + lr;
      const float bv = bias[col];
#pragma unroll
      for (int r = 0; r < 4; ++r) {
        const int row = row0 + r;
        float v = acc[mi][nj][r] + bv;
        if constexpr (EPI == EPI_BIAS_RELU_BF16) v = fmaxf(v, 0.0f);
        if constexpr (EPI == EPI_BIAS_RES_F32) {
          float* out = (float*)outp;
          out[(size_t)row * N + col] = v + res[(size_t)row * N + col];
        } else {
          ((u16*)outp)[(size_t)row * N + col] = f2bf(v);
        }
      }
    }
  }
}

// ---------------- GEMM 128x128 (m97 structure, proven) for proj/FC2 ----------------
template <int EPI>
__global__ __launch_bounds__(256, 3) void gemm_bt(
    const u16* __restrict__ A, const u16* __restrict__ Bt,
    const float* __restrict__ bias, const float* __restrict__ res,
    void* __restrict__ outp, int M, int N, int K)
{
  constexpr int BM = 128, BN = 128, BK = 64;
  __shared__ alignas(16) u16 As[BM][BK];
  __shared__ alignas(16) u16 Bs[BN][BK];
  const int tid  = threadIdx.x;
  const int lane = tid & 63;
  const int wv   = tid >> 6;
  const int wr   = wv >> 1, wc = wv & 1;
  const int lr   = lane & 15, lg = lane >> 4;

  const int q8  = (int)gridDim.x >> 3;
  const int lid = ((int)blockIdx.x & 7) * q8 + ((int)blockIdx.x >> 3);
  const int bm = (lid & 63) << 7;     // M/128 == 64, bm-fastest
  const int bn = (lid >> 6) << 7;

  f32x4 acc[4][4];
#pragma unroll
  for (int mi = 0; mi < 4; mi++)
#pragma unroll
    for (int nj = 0; nj < 4; nj++)
      acc[mi][nj] = (f32x4){0.f, 0.f, 0.f, 0.f};

  const int srow = tid >> 3;
  const int scol = (tid & 7) * 8;
  const u16* ga = &A [(size_t)(bm + srow) * K + scol];
  const u16* gb = &Bt[(size_t)(bn + srow) * K + scol];
  u16* as_dst = &As[0][0] + (size_t)tid * 8;
  u16* bs_dst = &Bs[0][0] + (size_t)tid * 8;

  for (int k0 = 0; k0 < K; k0 += BK) {
#pragma unroll
    for (int p = 0; p < 4; p++) {
      gload_lds16(ga + (size_t)p * 32 * K + k0, as_dst + p * 2048);
      gload_lds16(gb + (size_t)p * 32 * K + k0, bs_dst + p * 2048);
    }
    __syncthreads();
#pragma unroll
    for (int kk = 0; kk < BK; kk += 32) {
      bf16x8 af[4], bfr[4];
#pragma unroll
      for (int mi = 0; mi < 4; mi++)
        af[mi] = *reinterpret_cast<const bf16x8*>(&As[wr * 64 + mi * 16 + lr][kk + lg * 8]);
#pragma unroll
      for (int nj = 0; nj < 4; nj++)
        bfr[nj] = *reinterpret_cast<const bf16x8*>(&Bs[wc * 64 + nj * 16 + lr][kk + lg * 8]);
#pragma unroll
      for (int mi = 0; mi < 4; mi++)
#pragma unroll
        for (int nj = 0; nj < 4; nj++)
          acc[mi][nj] = __builtin_amdgcn_mfma_f32_16x16x32_bf16(af[mi], bfr[nj], acc[mi][nj], 0, 0, 0);
    }
    __syncthreads();
  }

#pragma unroll
  for (int mi = 0; mi < 4; mi++) {
#pragma unroll
    for (int nj = 0; nj < 4; nj++) {
      const int col = bn + wc * 64 + nj * 16 + lr;
      const float bv = bias[col];
#pragma unroll
      for (int r = 0; r < 4; r++) {
        const int row = bm + wr * 64 + mi * 16 + lg * 4 + r;
        float v = acc[mi][nj][r] + bv;
        if constexpr (EPI == EPI_BIAS_RELU_BF16) v = fmaxf(v, 0.0f);
        if constexpr (EPI == EPI_BIAS_RES_F32) {
          float* out = (float*)outp;
          out[(size_t)row * N + col] = v + res[(size_t)row * N + col];
        } else {
          ((u16*)outp)[(size_t)row * N + col] = f2bf(v);
        }
      }
    }
  }
}

// ---------------- V transpose: qkv[B][T][3C] (v part) -> vt[B][H][D][T] ----------------
__global__ __launch_bounds__(256) void build_vt(
    const u16* __restrict__ qkv, u16* __restrict__ vt)
{
  __shared__ u16 tile[64][80];
  const int t0 = blockIdx.x * 64;
  const int h  = blockIdx.y;
  const int b  = blockIdx.z;
  const int tid = threadIdx.x;
  const int rr = tid >> 3, cc = (tid & 7) * 8;
#pragma unroll
  for (int p = 0; p < 2; p++) {
    const int t = rr + p * 32;
    bf16x8 v = *reinterpret_cast<const bf16x8*>(
        &qkv[(size_t)(b * Tt + t0 + t) * C3 + 2 * Cc + h * Dd + cc]);
    *reinterpret_cast<bf16x8*>(&tile[t][cc]) = v;
  }
  __syncthreads();
#pragma unroll
  for (int p = 0; p < 2; p++) {
    const int d = rr + p * 32;
    union { u16 u[8]; int4 v; } o;
#pragma unroll
    for (int j = 0; j < 8; j++) o.u[j] = tile[cc + j][d];
    *reinterpret_cast<int4*>(&vt[(size_t)((b * Hh + h) * Dd + d) * Tt + t0 + cc]) = o.v;
  }
}

// ---------------- flash attention: KVBLK=64 (two subtiles/iter), pair-balanced ----------------
// Wave owns 32 q-rows; per iteration processes TWO 32-key subtiles with
// independent QK^T chains, one combined max/defer/exp batch, one PV pass.
// Halves the per-wave iteration count (65 -> ~33) to cut serial-chain stalls.
__global__ __launch_bounds__(256, 2) void flash_attn(
    const u16* __restrict__ qkv,   // [B][T][3C]
    const u16* __restrict__ vt,    // [B][H][D][T]
    u16* __restrict__ y)           // [B][T][C]
{
  const int tid = threadIdx.x, lane = tid & 63, wv = tid >> 6;
  const int l31 = lane & 31, hf = lane >> 5;

  // 512 blocks = 8 XCDs x 64; lid = bh*8 + pg (bh pinned to one XCD)
  const int bid = blockIdx.x;
  const int lid = (bid & 7) * 64 + (bid >> 3);
  const int bh = lid >> 3, pg = lid & 7;
  const int b = bh >> 4, h = bh & 15;
  const int pi = pg * 4 + wv;        // 0..31 -> tiles {pi, 63-pi}

  const u16* qbase = qkv + (size_t)b * Tt * C3 + h * Dd;
  const u16* kbase = qbase + Cc;
  const u16* vbase = vt + (size_t)bh * Dd * Tt;

#pragma unroll
  for (int ti = 0; ti < 2; ti++) {
    const int t = ti ? (63 - pi) : pi;
    const int q0 = t * 32;

    bf16x8 qf[4];
#pragma unroll
    for (int kc = 0; kc < 4; kc++)
      qf[kc] = *reinterpret_cast<const bf16x8*>(
          &qbase[(size_t)(q0 + l31) * C3 + kc * 16 + hf * 8]);

    f32x16 oacc[2];
#pragma unroll
    for (int i = 0; i < 16; i++) { oacc[0][i] = 0.f; oacc[1][i] = 0.f; }
    float mrun = -INFINITY, lpart = 0.0f;

    const u16* kptr = &kbase[(size_t)l31 * C3 + hf * 8];
    const u16* vp0 = &vbase[(size_t)l31 * Tt + hf * 8];
    const u16* vp1 = vp0 + (size_t)32 * Tt;

    bf16x8 kf0[4], kf1[4];
#pragma unroll
    for (int kc = 0; kc < 4; kc++)
      kf0[kc] = *reinterpret_cast<const bf16x8*>(kptr + kc * 16);
    if (t >= 1) {
#pragma unroll
      for (int kc = 0; kc < 4; kc++)
        kf1[kc] = *reinterpret_cast<const bf16x8*>(kptr + (size_t)32 * C3 + kc * 16);
    }

    int kt = 0;
    for (; kt + 1 <= t; kt += 2) {
      // V for both subtiles: vf_s[d0i][ch]
      bf16x8 vfa[2][2], vfb[2][2];
#pragma unroll
      for (int ch = 0; ch < 2; ch++) {
        vfa[0][ch] = *reinterpret_cast<const bf16x8*>(vp0 + ch * 16);
        vfa[1][ch] = *reinterpret_cast<const bf16x8*>(vp1 + ch * 16);
        vfb[0][ch] = *reinterpret_cast<const bf16x8*>(vp0 + 32 + ch * 16);
        vfb[1][ch] = *reinterpret_cast<const bf16x8*>(vp1 + 32 + ch * 16);
      }
      vp0 += 64; vp1 += 64;

      // two independent QK^T chains
      f32x16 s0, s1;
#pragma unroll
      for (int i = 0; i < 16; i++) { s0[i] = 0.f; s1[i] = 0.f; }
#pragma unroll
      for (int kc = 0; kc < 4; kc++) {
        s0 = __builtin_amdgcn_mfma_f32_32x32x16_bf16(kf0[kc], qf[kc], s0, 0, 0, 0);
        s1 = __builtin_amdgcn_mfma_f32_32x32x16_bf16(kf1[kc], qf[kc], s1, 0, 0, 0);
      }

      // prefetch next K pair (kt+2, kt+3); kt+3 may be past t (discarded)
      const bool pf = (kt + 2 <= t);
      bf16x8 kn0[4], kn1[4];
      if (pf) {
#pragma unroll
        for (int kc = 0; kc < 4; kc++) {
          kn0[kc] = *reinterpret_cast<const bf16x8*>(kptr + (size_t)64 * C3 + kc * 16);
          kn1[kc] = *reinterpret_cast<const bf16x8*>(kptr + (size_t)96 * C3 + kc * 16);
        }
      }
      kptr += (size_t)64 * C3;

      float sv0[16], sv1[16];
#pragma unroll
      for (int r = 0; r < 16; r++) { sv0[r] = s0[r]; sv1[r] = s1[r]; }
      if (kt + 1 == t) {   // subtile1 is the diagonal: mask key > q
#pragma unroll
        for (int r = 0; r < 16; r++)
          if ((r & 3) + 8 * (r >> 2) + 4 * hf > l31) sv1[r] = -INFINITY;
      }

      // combined max over 32
      float m0a = fmaxf(fmaxf(sv0[0], sv0[1]), fmaxf(sv0[2], sv0[3]));
      float m0b = fmaxf(fmaxf(sv0[4], sv0[5]), fmaxf(sv0[6], sv0[7]));
      float m0c = fmaxf(fmaxf(sv0[8], sv0[9]), fmaxf(sv0[10], sv0[11]));
      float m0d = fmaxf(fmaxf(sv0[12], sv0[13]), fmaxf(sv0[14], sv0[15]));
      float m1a = fmaxf(fmaxf(sv1[0], sv1[1]), fmaxf(sv1[2], sv1[3]));
      float m1b = fmaxf(fmaxf(sv1[4], sv1[5]), fmaxf(sv1[6], sv1[7]));
      float m1c = fmaxf(fmaxf(sv1[8], sv1[9]), fmaxf(sv1[10], sv1[11]));
      float m1d = fmaxf(fmaxf(sv1[12], sv1[13]), fmaxf(sv1[14], sv1[15]));
      float m8 = fmaxf(fmaxf(fmaxf(m0a, m0b), fmaxf(m0c, m0d)),
                       fmaxf(fmaxf(m1a, m1b), fmaxf(m1c, m1d)));
      m8 = xhalf_max(m8);

      if (!__all(m8 - mrun <= 64.0f)) {   // defer-max: 64 raw = 8 nats
        const float mnew  = fmaxf(mrun, m8);
        const float alpha = exp2_hw((mrun - mnew) * SCL2);
        lpart *= alpha;
#pragma unroll
        for (int i = 0; i < 16; i++) { oacc[0][i] *= alpha; oacc[1][i] *= alpha; }
        mrun = mnew;
      }

      const float ms = mrun * SCL2;
      float p0[16], p1[16];
#pragma unroll
      for (int r = 0; r < 16; r++) {
        p0[r] = exp2_hw(fmaf(sv0[r], SCL2, -ms));
        p1[r] = exp2_hw(fmaf(sv1[r], SCL2, -ms));
      }
      {
        float a0 = ((p0[0] + p0[1]) + (p0[2] + p0[3])) + ((p0[4] + p0[5]) + (p0[6] + p0[7]));
        float a1 = ((p0[8] + p0[9]) + (p0[10] + p0[11])) + ((p0[12] + p0[13]) + (p0[14] + p0[15]));
        float b0 = ((p1[0] + p1[1]) + (p1[2] + p1[3])) + ((p1[4] + p1[5]) + (p1[6] + p1[7]));
        float b1 = ((p1[8] + p1[9]) + (p1[10] + p1[11])) + ((p1[12] + p1[13]) + (p1[14] + p1[15]));
        lpart += (a0 + a1) + (b0 + b1);
      }

      // pack P^T for both subtiles
      unsigned pwa[2][4], pwb[2][4];
#pragma unroll
      for (int ch = 0; ch < 2; ch++) {
        const int bs = ch * 8;
        {
          unsigned w0 = pk2(p0[bs + 0], p0[bs + 1]);
          unsigned w1 = pk2(p0[bs + 2], p0[bs + 3]);
          unsigned w2 = pk2(p0[bs + 4], p0[bs + 5]);
          unsigned w3 = pk2(p0[bs + 6], p0[bs + 7]);
          uint2v r02 = plswap(w0, w2);
          uint2v r13 = plswap(w1, w3);
          pwa[ch][0] = r02[0]; pwa[ch][2] = r02[1];
          pwa[ch][1] = r13[0]; pwa[ch][3] = r13[1];
        }
        {
          unsigned w0 = pk2(p1[bs + 0], p1[bs + 1]);
          unsigned w1 = pk2(p1[bs + 2], p1[bs + 3]);
          unsigned w2 = pk2(p1[bs + 4], p1[bs + 5]);
          unsigned w3 = pk2(p1[bs + 6], p1[bs + 7]);
          uint2v r02 = plswap(w0, w2);
          uint2v r13 = plswap(w1, w3);
          pwb[ch][0] = r02[0]; pwb[ch][2] = r02[1];
          pwb[ch][1] = r13[0]; pwb[ch][3] = r13[1];
        }
      }

#pragma unroll
      for (int d0i = 0; d0i < 2; d0i++) {
#pragma unroll
        for (int ch = 0; ch < 2; ch++) {
          union { unsigned w[4]; bf16x8 v; } pb;
          pb.w[0] = pwa[ch][0]; pb.w[1] = pwa[ch][1];
          pb.w[2] = pwa[ch][2]; pb.w[3] = pwa[ch][3];
          oacc[d0i] = __builtin_amdgcn_mfma_f32_32x32x16_bf16(vfa[d0i][ch], pb.v, oacc[d0i], 0, 0, 0);
        }
#pragma unroll
        for (int ch = 0; ch < 2; ch++) {
          union { unsigned w[4]; bf16x8 v; } pb;
          pb.w[0] = pwb[ch][0]; pb.w[1] = pwb[ch][1];
          pb.w[2] = pwb[ch][2]; pb.w[3] = pwb[ch][3];
          oacc[d0i] = __builtin_amdgcn_mfma_f32_32x32x16_bf16(vfb[d0i][ch], pb.v, oacc[d0i], 0, 0, 0);
        }
      }

      if (pf) {
#pragma unroll
        for (int kc = 0; kc < 4; kc++) { kf0[kc] = kn0[kc]; kf1[kc] = kn1[kc]; }
      }
    }

    // trailing single 32-key tile (kt == t, even t): always the diagonal
    if (kt == t) {
      bf16x8 vfa[2][2];
#pragma unroll
      for (int ch = 0; ch < 2; ch++) {
        vfa[0][ch] = *reinterpret_cast<const bf16x8*>(vp0 + ch * 16);
        vfa[1][ch] = *reinterpret_cast<const bf16x8*>(vp1 + ch * 16);
      }

      f32x16 s0;
#pragma unroll
      for (int i = 0; i < 16; i++) s0[i] = 0.f;
#pragma unroll
      for (int kc = 0; kc < 4; kc++)
        s0 = __builtin_amdgcn_mfma_f32_32x32x16_bf16(kf0[kc], qf[kc], s0, 0, 0, 0);

      float sv0[16];
#pragma unroll
      for (int r = 0; r < 16; r++) {
        sv0[r] = s0[r];
        if ((r & 3) + 8 * (r >> 2) + 4 * hf > l31) sv0[r] = -INFINITY;
      }

      float ma = fmaxf(fmaxf(sv0[0], sv0[1]), fmaxf(sv0[2], sv0[3]));
      float mb = fmaxf(fmaxf(sv0[4], sv0[5]), fmaxf(sv0[6], sv0[7]));
      float mc = fmaxf(fmaxf(sv0[8], sv0[9]), fmaxf(sv0[10], sv0[11]));
      float md = fmaxf(fmaxf(sv0[12], sv0[13]), fmaxf(sv0[14], sv0[15]));
      float m8 = fmaxf(fmaxf(ma, mb), fmaxf(mc, md));
      m8 = xhalf_max(m8);

      if (!__all(m8 - mrun <= 64.0f)) {
        const float mnew  = fmaxf(mrun, m8);
        const float alpha = exp2_hw((mrun - mnew) * SCL2);
        lpart *= alpha;
#pragma unroll
        for (int i = 0; i < 16; i++) { oacc[0][i] *= alpha; oacc[1][i] *= alpha; }
        mrun = mnew;
      }

      const float ms = mrun * SCL2;
      float p0[16];
#pragma unroll
      for (int r = 0; r < 16; r++)
        p0[r] = exp2_hw(fmaf(sv0[r], SCL2, -ms));
      {
        float a0 = ((p0[0] + p0[1]) + (p0[2] + p0[3])) + ((p0[4] + p0[5]) + (p0[6] + p0[7]));
        float a1 = ((p0[8] + p0[9]) + (p0[10] + p0[11])) + ((p0[12] + p0[13]) + (p0[14] + p0[15]));
        lpart += a0 + a1;
      }

      unsigned pwa[2][4];
#pragma unroll
      for (int ch = 0; ch < 2; ch++) {
        const int bs = ch * 8;
        unsigned w0 = pk2(p0[bs + 0], p0[bs + 1]);
        unsigned w1 = pk2(p0[bs + 2], p0[bs + 3]);
        unsigned w2 = pk2(p0[bs + 4], p0[bs + 5]);
        unsigned w3 = pk2(p0[bs + 6], p0[bs + 7]);
        uint2v r02 = plswap(w0, w2);
        uint2v r13 = plswap(w1, w3);
        pwa[ch][0] = r02[0]; pwa[ch][2] = r02[1];
        pwa[ch][1] = r13[0]; pwa[ch][3] = r13[1];
      }

#pragma unroll
      for (int d0i = 0; d0i < 2; d0i++)
#pragma unroll
        for (int ch = 0; ch < 2; ch++) {
          union { unsigned w[4]; bf16x8 v; } pb;
          pb.w[0] = pwa[ch][0]; pb.w[1] = pwa[ch][1];
          pb.w[2] = pwa[ch][2]; pb.w[3] = pwa[ch][3];
          oacc[d0i] = __builtin_amdgcn_mfma_f32_32x32x16_bf16(vfa[d0i][ch], pb.v, oacc[d0i], 0, 0, 0);
        }
    }

    const float ls = xhalf_sum(lpart);
    const float inv = 1.0f / ls;
    u16* yrow = y + (size_t)(b * Tt + q0 + l31) * Cc + h * Dd;
#pragma unroll
    for (int d0i = 0; d0i < 2; d0i++)
#pragma unroll
      for (int qd = 0; qd < 4; qd++) {
        ushort4 o;
        o.x = bfn(oacc[d0i][qd * 4 + 0] * inv);
        o.y = bfn(oacc[d0i][qd * 4 + 1] * inv);
        o.z = bfn(oacc[d0i][qd * 4 + 2] * inv);
        o.w = bfn(oacc[d0i][qd * 4 + 3] * inv);
        *reinterpret_cast<ushort4*>(&yrow[d0i * 32 + qd * 8 + hf * 4]) = o;
      }
  }
}

// ---------------- launch ----------------
extern "C" void kernel_launch(void* const* d_in, const int* in_sizes, int n_in,
                              void* d_out, int out_size, void* d_ws, size_t ws_size,
                              hipStream_t stream)
{
  const float* x      = (const float*)d_in[0];
  const float* ln1_g  = (const float*)d_in[1];
  const float* ln1_b  = (const float*)d_in[2];
  const float* attn_w = (const float*)d_in[3];
  const float* attn_b = (const float*)d_in[4];
  const float* proj_w = (const float*)d_in[5];
  const float* proj_b = (const float*)d_in[6];
  const float* ln2_g  = (const float*)d_in[7];
  const float* ln2_b  = (const float*)d_in[8];
  const float* fc1_w  = (const float*)d_in[9];
  const float* fc1_b  = (const float*)d_in[10];
  const float* fc2_w  = (const float*)d_in[11];
  const float* fc2_b  = (const float*)d_in[12];
  float* out = (float*)d_out;

  char* ws = (char*)d_ws;
  size_t o = 0;
  auto alloc = [&](size_t bytes) { char* p = ws + o; o += bytes; return p; };
  u16* wqkv_t  = (u16*)alloc((size_t)C3 * Cc * 2);
  u16* wproj_t = (u16*)alloc((size_t)Cc * Cc * 2);
  u16* wfc1_t  = (u16*)alloc((size_t)4096 * Cc * 2);
  u16* wfc2_t  = (u16*)alloc((size_t)Cc * 4096 * 2);
  u16* h_bf    = (u16*)alloc((size_t)ROWS * Cc * 2);
  u16* y_bf    = (u16*)alloc((size_t)ROWS * Cc * 2);
  u16* qkv_raw = (u16*)alloc((size_t)ROWS * C3 * 2);
  u16* vt      = (u16*)alloc((size_t)Bb * Hh * Dd * Tt * 2);
  u16* hh      = qkv_raw; // aliases qkv_raw+vt, both dead by FC1 time

  wcast_t<<<dim3(C3 / 32, Cc / 32), 256, 0, stream>>>(attn_w, wqkv_t, Cc, C3);
  wcast_t<<<dim3(Cc / 32, Cc / 32), 256, 0, stream>>>(proj_w, wproj_t, Cc, Cc);
  wcast_t<<<dim3(4096 / 32, Cc / 32), 256, 0, stream>>>(fc1_w, wfc1_t, Cc, 4096);
  wcast_t<<<dim3(Cc / 32, 4096 / 32), 256, 0, stream>>>(fc2_w, wfc2_t, 4096, Cc);

  ln_kernel<<<ROWS, 256, 0, stream>>>(x, ln1_g, ln1_b, h_bf);
  gemm256<EPI_BIAS_BF16><<<32 * (C3 / 256), 512, 0, stream>>>(
      h_bf, wqkv_t, attn_b, nullptr, qkv_raw, ROWS, C3, Cc);
  build_vt<<<dim3(Tt / 64, Hh, Bb), 256, 0, stream>>>(qkv_raw, vt);
  flash_attn<<<dim3(512), 256, 0, stream>>>(qkv_raw, vt, y_bf);
  gemm_bt<EPI_BIAS_RES_F32><<<64 * (Cc / 128), 256, 0, stream>>>(
      y_bf, wproj_t, proj_b, x, out, ROWS, Cc, Cc);
  ln_kernel<<<ROWS, 256, 0, stream>>>(out, ln2_g, ln2_b, h_bf);
  gemm256<EPI_BIAS_RELU_BF16><<<32 * (4096 / 256), 512, 0, stream>>>(
      h_bf, wfc1_t, fc1_b, nullptr, hh, ROWS, 4096, Cc);
  gemm_bt<EPI_BIAS_RES_F32><<<64 * (Cc / 128), 256, 0, stream>>>(
      hh, wfc2_t, fc2_b, out, out, ROWS, Cc, 4096);
}